// Round 5
// baseline (490.678 us; speedup 1.0000x reference)
//
#include <hip/hip_runtime.h>
#include <hip/hip_bf16.h>

#define VOCAB 32000
#define NUM_CLASS 16
#define HID 256
#define KCAT 512          // concat(e, h) K dimension
#define BATCH 2048

typedef __attribute__((ext_vector_type(8))) __bf16 bf16x8;
typedef __attribute__((ext_vector_type(4))) float floatx4;

// RNE f32 -> bf16 (finite inputs)
__device__ __forceinline__ unsigned short f32_to_bf16_u16(float f) {
    union { float f; unsigned u; } a;
    a.f = f;
    unsigned r = a.u + 0x7fffu + ((a.u >> 16) & 1u);
    return (unsigned short)(r >> 16);
}

struct bf8v { unsigned short s[8]; };

// pack 8 f32 (2x float4) -> 8 bf16 words
__device__ __forceinline__ bf8v pack8(float4 u, float4 v) {
    bf8v o;
    o.s[0] = f32_to_bf16_u16(u.x); o.s[1] = f32_to_bf16_u16(u.y);
    o.s[2] = f32_to_bf16_u16(u.z); o.s[3] = f32_to_bf16_u16(u.w);
    o.s[4] = f32_to_bf16_u16(v.x); o.s[5] = f32_to_bf16_u16(v.y);
    o.s[6] = f32_to_bf16_u16(v.z); o.s[7] = f32_to_bf16_u16(v.w);
    return o;
}

// pack 8 f32 -> bf16x8 fragment (for MFMA A-operand built in registers)
__device__ __forceinline__ bf16x8 cvt8(float4 u, float4 v) {
    bf8v o = pack8(u, v);
    union { bf8v s; bf16x8 b; } c;
    c.s = o;
    return c.b;
}

// ---------------------------------------------------------------------------
// prep: stage Bcat (reused 64x per class -> staging pays) + bucket block.
// G staging removed (no reuse -> folded into rnn_gemm); Vw staging removed
// (out_gemm reads Vw f32 directly; saves ~49 MB of roundtrip traffic).
// Blocks 0..1023: Bcat[g][k] = [bf16(W[g][k]), bf16(U[g][k])]
// Block 1024: bucket z into perm/counts/bases (hides under staging blocks).
// ---------------------------------------------------------------------------
#define PREP_WU_BLOCKS (NUM_CLASS * HID * KCAT / 8 / 256)   // 1024

__global__ __launch_bounds__(256) void prep_bucket_kernel(
    const float* __restrict__ W, const float* __restrict__ U,
    const int* __restrict__ z,
    unsigned short* __restrict__ Bcat,
    int* __restrict__ perm, int* __restrict__ counts, int* __restrict__ bases)
{
    if (blockIdx.x == PREP_WU_BLOCKS) {
        // ---- bucket ----
        __shared__ int s_cnt[NUM_CLASS];
        __shared__ int s_off[NUM_CLASS];
        const int t = threadIdx.x;
        if (t < NUM_CLASS) s_cnt[t] = 0;
        __syncthreads();
        for (int c = t; c < BATCH; c += 256) atomicAdd(&s_cnt[z[c]], 1);
        __syncthreads();
        if (t == 0) {
            int acc = 0;
            for (int i = 0; i < NUM_CLASS; ++i) { s_off[i] = acc; acc += s_cnt[i]; }
        }
        __syncthreads();
        if (t < NUM_CLASS) { counts[t] = s_cnt[t]; bases[t] = s_off[t]; }
        __syncthreads();
        for (int c = t; c < BATCH; c += 256) {
            int p = atomicAdd(&s_off[z[c]], 1);
            perm[p] = c;
        }
        return;
    }

    const int tid = blockIdx.x * 256 + threadIdx.x;
    const int row = tid >> 6;             // g*HID + k
    const int j0  = (tid & 63) * 8;
    const float* src = (j0 < HID) ? (W + (size_t)row * HID + j0)
                                  : (U + (size_t)row * HID + (j0 - HID));
    float4 v0 = ((const float4*)src)[0];
    float4 v1 = ((const float4*)src)[1];
    *(bf8v*)(Bcat + (size_t)row * KCAT + j0) = pack8(v0, v1);
}

// ---------------------------------------------------------------------------
// Stage 1 per-class GEMM, A operand gathered DIRECTLY from E/h (f32) with
// in-register bf16 conversion (G staging eliminated — no reuse).
//   ht[c][k] = tanh( [E[x[c]],h[c]] . Bcat[g][k][:] )   (K = 512)
// ---------------------------------------------------------------------------
__global__ __launch_bounds__(256) void rnn_gemm_kernel(
    const int* __restrict__ x, const float* __restrict__ E,
    const float* __restrict__ h,
    const unsigned short* __restrict__ Bcat,  // NUM_CLASS x HID x KCAT
    const int* __restrict__ perm, const int* __restrict__ counts,
    const int* __restrict__ bases,
    float* __restrict__ ht_f32, unsigned short* __restrict__ ht_bf16)
{
    const int g = blockIdx.y;
    const int cnt = counts[g];
    const int mstart = blockIdx.x * 32;
    if (mstart >= cnt) return;
    const int base = bases[g];

    __shared__ int s_rows[32];
    __shared__ int s_x[32];
    if (threadIdx.x < 32) {
        int mi = mstart + threadIdx.x;
        int row = perm[base + (mi < cnt ? mi : cnt - 1)];
        s_rows[threadIdx.x] = row;
        s_x[threadIdx.x] = x[row];
    }
    __syncthreads();

    const int lane = threadIdx.x & 63;
    const int wave = threadIdx.x >> 6;
    const int n0   = wave * 64;
    const int lrow = lane & 15;
    const int quad = lane >> 4;
    const int kq   = quad * 8;

    const unsigned short* Bg = Bcat + (size_t)g * HID * KCAT;

    floatx4 acc[2][4] = {};

    // K half 1: A from E[x[c]]
#pragma unroll 4
    for (int k0 = 0; k0 < 256; k0 += 32) {
        bf16x8 a[2], b[4];
#pragma unroll
        for (int mi = 0; mi < 2; ++mi) {
            const float* s = E + (size_t)s_x[mi * 16 + lrow] * HID + k0 + kq;
            a[mi] = cvt8(((const float4*)s)[0], ((const float4*)s)[1]);
        }
#pragma unroll
        for (int ni = 0; ni < 4; ++ni)
            b[ni] = *(const bf16x8*)(Bg + (size_t)(n0 + ni * 16 + lrow) * KCAT + k0 + kq);
#pragma unroll
        for (int mi = 0; mi < 2; ++mi)
#pragma unroll
            for (int ni = 0; ni < 4; ++ni)
                acc[mi][ni] = __builtin_amdgcn_mfma_f32_16x16x32_bf16(
                    a[mi], b[ni], acc[mi][ni], 0, 0, 0);
    }
    // K half 2: A from h[c]
#pragma unroll 4
    for (int k0 = 256; k0 < 512; k0 += 32) {
        bf16x8 a[2], b[4];
#pragma unroll
        for (int mi = 0; mi < 2; ++mi) {
            const float* s = h + (size_t)s_rows[mi * 16 + lrow] * HID + (k0 - 256) + kq;
            a[mi] = cvt8(((const float4*)s)[0], ((const float4*)s)[1]);
        }
#pragma unroll
        for (int ni = 0; ni < 4; ++ni)
            b[ni] = *(const bf16x8*)(Bg + (size_t)(n0 + ni * 16 + lrow) * KCAT + k0 + kq);
#pragma unroll
        for (int mi = 0; mi < 2; ++mi)
#pragma unroll
            for (int ni = 0; ni < 4; ++ni)
                acc[mi][ni] = __builtin_amdgcn_mfma_f32_16x16x32_bf16(
                    a[mi], b[ni], acc[mi][ni], 0, 0, 0);
    }

#pragma unroll
    for (int mi = 0; mi < 2; ++mi) {
#pragma unroll
        for (int r = 0; r < 4; ++r) {
            const int midx = mi * 16 + quad * 4 + r;
            if (mstart + midx >= cnt) continue;
            const int c = s_rows[midx];
#pragma unroll
            for (int ni = 0; ni < 4; ++ni) {
                const int k = n0 + ni * 16 + lrow;
                const float v = tanhf(acc[mi][ni][r]);
                ht_f32 [(size_t)c * HID + k] = v;
                ht_bf16[(size_t)c * HID + k] = f32_to_bf16_u16(v);
            }
        }
    }
}

// ---------------------------------------------------------------------------
// Stage 2: logits = ht . Vw^T + Vb   (M=2048, N=32000, K=256)
// 128x128 tile, BK=32, double-buffered, PLAIN reg->LDS staging for BOTH
// operands (no global_load_lds: the async-DMA + ds_write mix is the prime
// suspect for the R3 container wedge). A: ht bf16 copied through regs.
// B: Vw read f32 directly (no prep roundtrip) + in-reg cvt. Issue-early /
// write-late: loads at top of iter, vmcnt drain after MFMA, one barrier.
// Both-sides XOR swizzle: slot s of row r holds chunk s ^ ((r>>1)&3);
// reads resolve to chunk quad -> 2-way bank access (free).
// ---------------------------------------------------------------------------
__global__ __launch_bounds__(256) void out_gemm_kernel(
    const unsigned short* __restrict__ A,   // ht bf16, 2048 x 256
    const float* __restrict__ Bf,           // Vw f32, 32000 x 256
    const float* __restrict__ Vb,
    float* __restrict__ C)                  // 2048 x 32000
{
    __shared__ unsigned short sA[2][128 * 32];  // 8 KB per buffer
    __shared__ unsigned short sB[2][128 * 32];

    // bijective XCD swizzle (4000 = 8 * 500), n-major within an XCD chunk.
    const int id  = blockIdx.x;
    const int sid = (id & 7) * 500 + (id >> 3);
    const int n0  = (sid >> 4) * 128;       // 250 n-panels
    const int m0  = (sid & 15) * 128;       // 16 m-panels

    const int lane = threadIdx.x & 63;
    const int wave = threadIdx.x >> 6;
    const int wr = wave >> 1, wc = wave & 1;
    const int lrow = lane & 15;
    const int quad = lane >> 4;

    // staging geometry (same for A and B): thread t owns row t>>1 and the
    // two chunks (t&1)*2 + {0,1}; they land in slots chunk ^ ((row>>1)&3).
    const int srow = threadIdx.x >> 1;           // 0..127
    const int sc0  = (threadIdx.x & 1) * 2;
    const int ss0  = (sc0    ) ^ ((srow >> 1) & 3);
    const int ss1  = (sc0 + 1) ^ ((srow >> 1) & 3);
    const unsigned short* asrc = A  + (size_t)(m0 + srow) * HID + sc0 * 8;
    const float*          bsrc = Bf + (size_t)(n0 + srow) * HID + sc0 * 8;

    // read-side slot: chunk quad lives at slot quad ^ ((row>>1)&3);
    // for all rows used, (row>>1)&3 == (lrow>>1)&3.
    const int rslot = quad ^ ((lrow >> 1) & 3);

    floatx4 acc[4][4] = {};

    // prologue: stage tile 0
    {
        bf8v  a0 = ((const bf8v*)asrc)[0];
        bf8v  a1 = ((const bf8v*)asrc)[1];
        float4 w0 = ((const float4*)bsrc)[0], w1 = ((const float4*)bsrc)[1];
        float4 w2 = ((const float4*)bsrc)[2], w3 = ((const float4*)bsrc)[3];
        *(bf8v*)&sA[0][srow * 32 + ss0 * 8] = a0;
        *(bf8v*)&sA[0][srow * 32 + ss1 * 8] = a1;
        *(bf8v*)&sB[0][srow * 32 + ss0 * 8] = pack8(w0, w1);
        *(bf8v*)&sB[0][srow * 32 + ss1 * 8] = pack8(w2, w3);
    }
    __syncthreads();

#pragma unroll
    for (int kt = 0; kt < 8; ++kt) {
        const int cur = kt & 1;
        bf8v a0, a1;
        float4 w0, w1, w2, w3;
        if (kt < 7) {   // issue-early: next tile's global loads
            const int k0n = (kt + 1) * 32;
            const unsigned short* as = asrc + k0n;
            const float*          bs = bsrc + k0n;
            a0 = ((const bf8v*)as)[0];
            a1 = ((const bf8v*)as)[1];
            w0 = ((const float4*)bs)[0]; w1 = ((const float4*)bs)[1];
            w2 = ((const float4*)bs)[2]; w3 = ((const float4*)bs)[3];
        }

        bf16x8 a[4], b[4];
#pragma unroll
        for (int mi = 0; mi < 4; ++mi) {
            const int ra = wr * 64 + mi * 16 + lrow;
            a[mi] = *(const bf16x8*)&sA[cur][ra * 32 + rslot * 8];
        }
#pragma unroll
        for (int ni = 0; ni < 4; ++ni) {
            const int rb = wc * 64 + ni * 16 + lrow;
            b[ni] = *(const bf16x8*)&sB[cur][rb * 32 + rslot * 8];
        }
#pragma unroll
        for (int mi = 0; mi < 4; ++mi)
#pragma unroll
            for (int ni = 0; ni < 4; ++ni)
                acc[mi][ni] = __builtin_amdgcn_mfma_f32_16x16x32_bf16(
                    a[mi], b[ni], acc[mi][ni], 0, 0, 0);

        if (kt < 7) {   // write-late: loads had the whole MFMA phase in flight
            *(bf8v*)&sA[cur ^ 1][srow * 32 + ss0 * 8] = a0;
            *(bf8v*)&sA[cur ^ 1][srow * 32 + ss1 * 8] = a1;
            *(bf8v*)&sB[cur ^ 1][srow * 32 + ss0 * 8] = pack8(w0, w1);
            *(bf8v*)&sB[cur ^ 1][srow * 32 + ss1 * 8] = pack8(w2, w3);
        }
        __syncthreads();
    }

    const int m_wave = m0 + wr * 64;
    const int n_wave = n0 + wc * 64;
    const int row_q  = quad * 4;
#pragma unroll
    for (int ni = 0; ni < 4; ++ni) {
        const int col = n_wave + ni * 16 + lrow;
        const float vb = Vb[col];
#pragma unroll
        for (int mi = 0; mi < 4; ++mi) {
            float* cp = C + (size_t)(m_wave + mi * 16 + row_q) * VOCAB + col;
#pragma unroll
            for (int r = 0; r < 4; ++r)
                __builtin_nontemporal_store(acc[mi][ni][r] + vb, cp + (size_t)r * VOCAB);
        }
    }
}

extern "C" void kernel_launch(void* const* d_in, const int* in_sizes, int n_in,
                              void* d_out, int out_size, void* d_ws, size_t ws_size,
                              hipStream_t stream) {
    const int*   x  = (const int*)d_in[0];
    const int*   z  = (const int*)d_in[1];
    const float* h  = (const float*)d_in[2];
    const float* E  = (const float*)d_in[3];
    const float* Vw = (const float*)d_in[4];
    const float* Vb = (const float*)d_in[5];
    const float* W  = (const float*)d_in[6];
    const float* U  = (const float*)d_in[7];

    float* logits = (float*)d_out;
    float* ht_out = logits + (size_t)BATCH * VOCAB;

    // workspace layout
    char* p = (char*)d_ws;
    unsigned short* ht_bf = (unsigned short*)p;  p += (size_t)BATCH * HID * 2;
    unsigned short* Bcat  = (unsigned short*)p;  p += (size_t)NUM_CLASS * HID * KCAT * 2;
    int* perm   = (int*)p;  p += BATCH * 4;
    int* counts = (int*)p;  p += NUM_CLASS * 4;
    int* bases  = (int*)p;  p += NUM_CLASS * 4;

    prep_bucket_kernel<<<PREP_WU_BLOCKS + 1, 256, 0, stream>>>(
        W, U, z, Bcat, perm, counts, bases);
    rnn_gemm_kernel<<<dim3(BATCH / 32, NUM_CLASS), 256, 0, stream>>>(
        x, E, h, Bcat, perm, counts, bases, ht_out, ht_bf);
    out_gemm_kernel<<<4000, 256, 0, stream>>>(ht_bf, Vw, Vb, logits);
}

// Round 6
// 485.373 us; speedup vs baseline: 1.0109x; 1.0109x over previous
//
#include <hip/hip_runtime.h>
#include <hip/hip_bf16.h>

#define VOCAB 32000
#define NUM_CLASS 16
#define HID 256
#define KCAT 512          // concat(e, h) K dimension
#define BATCH 2048

typedef __attribute__((ext_vector_type(8))) __bf16 bf16x8;
typedef __attribute__((ext_vector_type(4))) float floatx4;

// RNE f32 -> bf16 (finite inputs)
__device__ __forceinline__ unsigned short f32_to_bf16_u16(float f) {
    union { float f; unsigned u; } a;
    a.f = f;
    unsigned r = a.u + 0x7fffu + ((a.u >> 16) & 1u);
    return (unsigned short)(r >> 16);
}

struct bf8v { unsigned short s[8]; };

// pack 8 f32 (2x float4) -> 8 bf16 words
__device__ __forceinline__ bf8v pack8(float4 u, float4 v) {
    bf8v o;
    o.s[0] = f32_to_bf16_u16(u.x); o.s[1] = f32_to_bf16_u16(u.y);
    o.s[2] = f32_to_bf16_u16(u.z); o.s[3] = f32_to_bf16_u16(u.w);
    o.s[4] = f32_to_bf16_u16(v.x); o.s[5] = f32_to_bf16_u16(v.y);
    o.s[6] = f32_to_bf16_u16(v.z); o.s[7] = f32_to_bf16_u16(v.w);
    return o;
}

// pack 8 f32 -> bf16x8 fragment (for MFMA A-operand built in registers)
__device__ __forceinline__ bf16x8 cvt8(float4 u, float4 v) {
    union { bf8v s; bf16x8 b; } c;
    c.s = pack8(u, v);
    return c.b;
}

// ---------------------------------------------------------------------------
// prep: stage Bcat (reused 64x per class -> staging pays) + bucket block.
// Blocks 0..1023: Bcat[g][k] = [bf16(W[g][k]), bf16(U[g][k])]
// Block 1024: bucket z into perm/counts/bases (hides under staging blocks).
// ---------------------------------------------------------------------------
#define PREP_WU_BLOCKS (NUM_CLASS * HID * KCAT / 8 / 256)   // 1024

__global__ __launch_bounds__(256) void prep_bucket_kernel(
    const float* __restrict__ W, const float* __restrict__ U,
    const int* __restrict__ z,
    unsigned short* __restrict__ Bcat,
    int* __restrict__ perm, int* __restrict__ counts, int* __restrict__ bases)
{
    if (blockIdx.x == PREP_WU_BLOCKS) {
        __shared__ int s_cnt[NUM_CLASS];
        __shared__ int s_off[NUM_CLASS];
        const int t = threadIdx.x;
        if (t < NUM_CLASS) s_cnt[t] = 0;
        __syncthreads();
        for (int c = t; c < BATCH; c += 256) atomicAdd(&s_cnt[z[c]], 1);
        __syncthreads();
        if (t == 0) {
            int acc = 0;
            for (int i = 0; i < NUM_CLASS; ++i) { s_off[i] = acc; acc += s_cnt[i]; }
        }
        __syncthreads();
        if (t < NUM_CLASS) { counts[t] = s_cnt[t]; bases[t] = s_off[t]; }
        __syncthreads();
        for (int c = t; c < BATCH; c += 256) {
            int p = atomicAdd(&s_off[z[c]], 1);
            perm[p] = c;
        }
        return;
    }

    const int tid = blockIdx.x * 256 + threadIdx.x;
    const int row = tid >> 6;             // g*HID + k
    const int j0  = (tid & 63) * 8;
    const float* src = (j0 < HID) ? (W + (size_t)row * HID + j0)
                                  : (U + (size_t)row * HID + (j0 - HID));
    float4 v0 = ((const float4*)src)[0];
    float4 v1 = ((const float4*)src)[1];
    *(bf8v*)(Bcat + (size_t)row * KCAT + j0) = pack8(v0, v1);
}

// ---------------------------------------------------------------------------
// Stage 1 per-class GEMM, A operand gathered DIRECTLY from E/h (f32) with
// in-register bf16 conversion.  ht[c][k] = tanh([E[x[c]],h[c]] . Bcat[g][k])
// ---------------------------------------------------------------------------
__global__ __launch_bounds__(256) void rnn_gemm_kernel(
    const int* __restrict__ x, const float* __restrict__ E,
    const float* __restrict__ h,
    const unsigned short* __restrict__ Bcat,  // NUM_CLASS x HID x KCAT
    const int* __restrict__ perm, const int* __restrict__ counts,
    const int* __restrict__ bases,
    float* __restrict__ ht_f32, unsigned short* __restrict__ ht_bf16)
{
    const int g = blockIdx.y;
    const int cnt = counts[g];
    const int mstart = blockIdx.x * 32;
    if (mstart >= cnt) return;
    const int base = bases[g];

    __shared__ int s_rows[32];
    __shared__ int s_x[32];
    if (threadIdx.x < 32) {
        int mi = mstart + threadIdx.x;
        int row = perm[base + (mi < cnt ? mi : cnt - 1)];
        s_rows[threadIdx.x] = row;
        s_x[threadIdx.x] = x[row];
    }
    __syncthreads();

    const int lane = threadIdx.x & 63;
    const int wave = threadIdx.x >> 6;
    const int n0   = wave * 64;
    const int lrow = lane & 15;
    const int quad = lane >> 4;
    const int kq   = quad * 8;

    const unsigned short* Bg = Bcat + (size_t)g * HID * KCAT;

    floatx4 acc[2][4] = {};

    // K half 1: A from E[x[c]]
#pragma unroll 4
    for (int k0 = 0; k0 < 256; k0 += 32) {
        bf16x8 a[2], b[4];
#pragma unroll
        for (int mi = 0; mi < 2; ++mi) {
            const float* s = E + (size_t)s_x[mi * 16 + lrow] * HID + k0 + kq;
            a[mi] = cvt8(((const float4*)s)[0], ((const float4*)s)[1]);
        }
#pragma unroll
        for (int ni = 0; ni < 4; ++ni)
            b[ni] = *(const bf16x8*)(Bg + (size_t)(n0 + ni * 16 + lrow) * KCAT + k0 + kq);
#pragma unroll
        for (int mi = 0; mi < 2; ++mi)
#pragma unroll
            for (int ni = 0; ni < 4; ++ni)
                acc[mi][ni] = __builtin_amdgcn_mfma_f32_16x16x32_bf16(
                    a[mi], b[ni], acc[mi][ni], 0, 0, 0);
    }
    // K half 2: A from h[c]
#pragma unroll 4
    for (int k0 = 256; k0 < 512; k0 += 32) {
        bf16x8 a[2], b[4];
#pragma unroll
        for (int mi = 0; mi < 2; ++mi) {
            const float* s = h + (size_t)s_rows[mi * 16 + lrow] * HID + (k0 - 256) + kq;
            a[mi] = cvt8(((const float4*)s)[0], ((const float4*)s)[1]);
        }
#pragma unroll
        for (int ni = 0; ni < 4; ++ni)
            b[ni] = *(const bf16x8*)(Bg + (size_t)(n0 + ni * 16 + lrow) * KCAT + k0 + kq);
#pragma unroll
        for (int mi = 0; mi < 2; ++mi)
#pragma unroll
            for (int ni = 0; ni < 4; ++ni)
                acc[mi][ni] = __builtin_amdgcn_mfma_f32_16x16x32_bf16(
                    a[mi], b[ni], acc[mi][ni], 0, 0, 0);
    }

#pragma unroll
    for (int mi = 0; mi < 2; ++mi) {
#pragma unroll
        for (int r = 0; r < 4; ++r) {
            const int midx = mi * 16 + quad * 4 + r;
            if (mstart + midx >= cnt) continue;
            const int c = s_rows[midx];
#pragma unroll
            for (int ni = 0; ni < 4; ++ni) {
                const int k = n0 + ni * 16 + lrow;
                const float v = tanhf(acc[mi][ni][r]);
                ht_f32 [(size_t)c * HID + k] = v;
                ht_bf16[(size_t)c * HID + k] = f32_to_bf16_u16(v);
            }
        }
    }
}

// ---------------------------------------------------------------------------
// Stage 2: logits = ht . Vw^T + Vb   (M=2048, N=32000, K=256)
// B-STATIONARY, BARRIER-FREE: each block owns a 64-row Vw panel (full K) in
// 32 KB LDS, staged ONCE (f32 -> bf16, XOR-swizzled: chunk cc of row r at
// slot cc^(r&7) -> uniform bank access on both sides). After the single
// barrier, 4 m-steps x 8 K-steps of {A 16B global loads (ht_bf, L2-hot),
// swizzled ds_read, MFMA} run with no synchronization -> latency hidden by
// unrolled pipeline + 5 blocks/CU. XCD-chunked grid: the 4 m-ranges of a
// panel land on one XCD -> Vw HBM-fetched once, L2 re-served.
// ---------------------------------------------------------------------------
__global__ __launch_bounds__(256) void out_gemm_kernel(
    const unsigned short* __restrict__ A,   // ht bf16, 2048 x 256
    const float* __restrict__ Bf,           // Vw f32, 32000 x 256
    const float* __restrict__ Vb,
    float* __restrict__ C)                  // 2048 x 32000
{
    __shared__ unsigned short sB[64 * 256];   // 32 KB bf16 B-panel

    // 2000 blocks = 500 n-panels x 4 m-ranges, XCD-chunked n-major.
    const int id  = blockIdx.x;
    const int sid = (id & 7) * 250 + (id >> 3);
    const int n0  = (sid >> 2) * 64;        // n-panel (0..499)
    const int m0  = (sid & 3) * 512;        // m-range

    const int t    = threadIdx.x;
    const int lane = t & 63;
    const int wave = t >> 6;
    const int lrow = lane & 15;
    const int quad = lane >> 4;
    const int wm   = (wave >> 1) * 64;      // wave m-offset in 128-row m-step
    const int wn   = (wave & 1) * 32;       // wave n-offset in 64-col panel

    // ---- stage B panel once: thread t = row t>>2, chunks (t&3)*8 + j ----
    {
        const int row = t >> 2;
        const int cc0 = (t & 3) * 8;
        const float* src = Bf + (size_t)(n0 + row) * HID + cc0 * 8;
#pragma unroll
        for (int j = 0; j < 8; ++j) {
            float4 u = ((const float4*)src)[j * 2];
            float4 v = ((const float4*)src)[j * 2 + 1];
            const int slot = (cc0 + j) ^ (row & 7);
            *(bf8v*)&sB[row * 256 + slot * 8] = pack8(u, v);
        }
    }
    __syncthreads();      // the only barrier in this kernel

    const float vb0 = Vb[n0 + wn + lrow];
    const float vb1 = Vb[n0 + wn + 16 + lrow];

    for (int ms = 0; ms < 4; ++ms) {
        const int mbase = m0 + ms * 128 + wm;
        floatx4 acc[4][2] = {};
#pragma unroll
        for (int kt = 0; kt < 8; ++kt) {
            bf16x8 a[4], b[2];
#pragma unroll
            for (int mi = 0; mi < 4; ++mi)
                a[mi] = *(const bf16x8*)(
                    A + (size_t)(mbase + mi * 16 + lrow) * HID + kt * 32 + quad * 8);
#pragma unroll
            for (int ni = 0; ni < 2; ++ni) {
                const int rb   = wn + ni * 16 + lrow;
                const int slot = (kt * 4 + quad) ^ (rb & 7);
                b[ni] = *(const bf16x8*)&sB[rb * 256 + slot * 8];
            }
#pragma unroll
            for (int mi = 0; mi < 4; ++mi)
#pragma unroll
                for (int ni = 0; ni < 2; ++ni)
                    acc[mi][ni] = __builtin_amdgcn_mfma_f32_16x16x32_bf16(
                        a[mi], b[ni], acc[mi][ni], 0, 0, 0);
        }

#pragma unroll
        for (int ni = 0; ni < 2; ++ni) {
            const int col = n0 + wn + ni * 16 + lrow;
            const float vb = ni ? vb1 : vb0;
#pragma unroll
            for (int mi = 0; mi < 4; ++mi) {
                float* cp = C + (size_t)(mbase + mi * 16 + quad * 4) * VOCAB + col;
#pragma unroll
                for (int r = 0; r < 4; ++r)
                    __builtin_nontemporal_store(acc[mi][ni][r] + vb,
                                                cp + (size_t)r * VOCAB);
            }
        }
    }
}

extern "C" void kernel_launch(void* const* d_in, const int* in_sizes, int n_in,
                              void* d_out, int out_size, void* d_ws, size_t ws_size,
                              hipStream_t stream) {
    const int*   x  = (const int*)d_in[0];
    const int*   z  = (const int*)d_in[1];
    const float* h  = (const float*)d_in[2];
    const float* E  = (const float*)d_in[3];
    const float* Vw = (const float*)d_in[4];
    const float* Vb = (const float*)d_in[5];
    const float* W  = (const float*)d_in[6];
    const float* U  = (const float*)d_in[7];

    float* logits = (float*)d_out;
    float* ht_out = logits + (size_t)BATCH * VOCAB;

    // workspace layout
    char* p = (char*)d_ws;
    unsigned short* ht_bf = (unsigned short*)p;  p += (size_t)BATCH * HID * 2;
    unsigned short* Bcat  = (unsigned short*)p;  p += (size_t)NUM_CLASS * HID * KCAT * 2;
    int* perm   = (int*)p;  p += BATCH * 4;
    int* counts = (int*)p;  p += NUM_CLASS * 4;
    int* bases  = (int*)p;  p += NUM_CLASS * 4;

    prep_bucket_kernel<<<PREP_WU_BLOCKS + 1, 256, 0, stream>>>(
        W, U, z, Bcat, perm, counts, bases);
    rnn_gemm_kernel<<<dim3(BATCH / 32, NUM_CLASS), 256, 0, stream>>>(
        x, E, h, Bcat, perm, counts, bases, ht_out, ht_bf);
    out_gemm_kernel<<<2000, 256, 0, stream>>>(ht_bf, Vw, Vb, logits);
}

// Round 7
// 429.024 us; speedup vs baseline: 1.1437x; 1.1313x over previous
//
#include <hip/hip_runtime.h>
#include <hip/hip_bf16.h>

#define VOCAB 32000
#define NUM_CLASS 16
#define HID 256
#define KCAT 512          // concat(e, h) K dimension
#define BATCH 2048

typedef __attribute__((ext_vector_type(8))) __bf16 bf16x8;
typedef __attribute__((ext_vector_type(4))) float floatx4;

// RNE f32 -> bf16 (finite inputs)
__device__ __forceinline__ unsigned short f32_to_bf16_u16(float f) {
    union { float f; unsigned u; } a;
    a.f = f;
    unsigned r = a.u + 0x7fffu + ((a.u >> 16) & 1u);
    return (unsigned short)(r >> 16);
}

struct bf8v { unsigned short s[8]; };

// pack 8 f32 (2x float4) -> 8 bf16 words
__device__ __forceinline__ bf8v pack8(float4 u, float4 v) {
    bf8v o;
    o.s[0] = f32_to_bf16_u16(u.x); o.s[1] = f32_to_bf16_u16(u.y);
    o.s[2] = f32_to_bf16_u16(u.z); o.s[3] = f32_to_bf16_u16(u.w);
    o.s[4] = f32_to_bf16_u16(v.x); o.s[5] = f32_to_bf16_u16(v.y);
    o.s[6] = f32_to_bf16_u16(v.z); o.s[7] = f32_to_bf16_u16(v.w);
    return o;
}

// pack 8 f32 -> bf16x8 fragment (for MFMA A-operand built in registers)
__device__ __forceinline__ bf16x8 cvt8(float4 u, float4 v) {
    union { bf8v s; bf16x8 b; } c;
    c.s = pack8(u, v);
    return c.b;
}

// async global->LDS, 16B per lane. LDS dest is wave-uniform base + lane*16.
__device__ __forceinline__ void lds_load16(unsigned short* lds, const unsigned short* g) {
    __builtin_amdgcn_global_load_lds(
        (const __attribute__((address_space(1))) unsigned int*)g,
        (__attribute__((address_space(3))) unsigned int*)lds, 16, 0, 0);
}

// ---------------------------------------------------------------------------
// Fused prep + bucket.
// Blocks 0..1023:      Bcat[g][k] = [bf16(W[g][k]), bf16(U[g][k])]
// Blocks 1024..5023:   Vw_bf = bf16(Vw)   (needed for out_gemm's direct
//                      bf16 gload_lds staging — Vw-f32-direct REGRESSED)
// Block 5024:          bucket z into perm/counts/bases (hides under others)
// ---------------------------------------------------------------------------
#define PREP_WU_BLOCKS (NUM_CLASS * HID * KCAT / 8 / 256)   // 1024
#define PREP_VW_BLOCKS (VOCAB * HID / 8 / 256)              // 4000
#define PREP_BLOCKS    (PREP_WU_BLOCKS + PREP_VW_BLOCKS)    // 5024

__global__ __launch_bounds__(256) void prep_bucket_kernel(
    const float* __restrict__ W, const float* __restrict__ U,
    const float* __restrict__ Vw, const int* __restrict__ z,
    unsigned short* __restrict__ Bcat, unsigned short* __restrict__ Vw_bf,
    int* __restrict__ perm, int* __restrict__ counts, int* __restrict__ bases)
{
    if (blockIdx.x == PREP_BLOCKS) {
        // ---- bucket ----
        __shared__ int s_cnt[NUM_CLASS];
        __shared__ int s_off[NUM_CLASS];
        const int t = threadIdx.x;
        if (t < NUM_CLASS) s_cnt[t] = 0;
        __syncthreads();
        for (int c = t; c < BATCH; c += 256) atomicAdd(&s_cnt[z[c]], 1);
        __syncthreads();
        if (t == 0) {
            int acc = 0;
            for (int i = 0; i < NUM_CLASS; ++i) { s_off[i] = acc; acc += s_cnt[i]; }
        }
        __syncthreads();
        if (t < NUM_CLASS) { counts[t] = s_cnt[t]; bases[t] = s_off[t]; }
        __syncthreads();
        for (int c = t; c < BATCH; c += 256) {
            int p = atomicAdd(&s_off[z[c]], 1);
            perm[p] = c;
        }
        return;
    }

    const float* src;
    unsigned short* dst;
    if (blockIdx.x < PREP_WU_BLOCKS) {
        const int tid = blockIdx.x * 256 + threadIdx.x;
        const int row = tid >> 6;             // g*HID + k
        const int j0  = (tid & 63) * 8;
        src = (j0 < HID) ? (W + (size_t)row * HID + j0)
                         : (U + (size_t)row * HID + (j0 - HID));
        dst = Bcat + (size_t)row * KCAT + j0;
    } else {
        const int idx = (blockIdx.x - PREP_WU_BLOCKS) * 256 + threadIdx.x;
        src = Vw + (size_t)idx * 8;
        dst = Vw_bf + (size_t)idx * 8;
    }
    float4 v0 = ((const float4*)src)[0];
    float4 v1 = ((const float4*)src)[1];
    *(bf8v*)dst = pack8(v0, v1);
}

// ---------------------------------------------------------------------------
// Stage 1 per-class GEMM, A operand gathered DIRECTLY from E/h (f32) with
// in-register bf16 conversion.  ht[c][k] = tanh([E[x[c]],h[c]] . Bcat[g][k])
// (verified passing in R5/R6)
// ---------------------------------------------------------------------------
__global__ __launch_bounds__(256) void rnn_gemm_kernel(
    const int* __restrict__ x, const float* __restrict__ E,
    const float* __restrict__ h,
    const unsigned short* __restrict__ Bcat,  // NUM_CLASS x HID x KCAT
    const int* __restrict__ perm, const int* __restrict__ counts,
    const int* __restrict__ bases,
    float* __restrict__ ht_f32, unsigned short* __restrict__ ht_bf16)
{
    const int g = blockIdx.y;
    const int cnt = counts[g];
    const int mstart = blockIdx.x * 32;
    if (mstart >= cnt) return;
    const int base = bases[g];

    __shared__ int s_rows[32];
    __shared__ int s_x[32];
    if (threadIdx.x < 32) {
        int mi = mstart + threadIdx.x;
        int row = perm[base + (mi < cnt ? mi : cnt - 1)];
        s_rows[threadIdx.x] = row;
        s_x[threadIdx.x] = x[row];
    }
    __syncthreads();

    const int lane = threadIdx.x & 63;
    const int wave = threadIdx.x >> 6;
    const int n0   = wave * 64;
    const int lrow = lane & 15;
    const int quad = lane >> 4;
    const int kq   = quad * 8;

    const unsigned short* Bg = Bcat + (size_t)g * HID * KCAT;

    floatx4 acc[2][4] = {};

    // K half 1: A from E[x[c]]
#pragma unroll 4
    for (int k0 = 0; k0 < 256; k0 += 32) {
        bf16x8 a[2], b[4];
#pragma unroll
        for (int mi = 0; mi < 2; ++mi) {
            const float* s = E + (size_t)s_x[mi * 16 + lrow] * HID + k0 + kq;
            a[mi] = cvt8(((const float4*)s)[0], ((const float4*)s)[1]);
        }
#pragma unroll
        for (int ni = 0; ni < 4; ++ni)
            b[ni] = *(const bf16x8*)(Bg + (size_t)(n0 + ni * 16 + lrow) * KCAT + k0 + kq);
#pragma unroll
        for (int mi = 0; mi < 2; ++mi)
#pragma unroll
            for (int ni = 0; ni < 4; ++ni)
                acc[mi][ni] = __builtin_amdgcn_mfma_f32_16x16x32_bf16(
                    a[mi], b[ni], acc[mi][ni], 0, 0, 0);
    }
    // K half 2: A from h[c]
#pragma unroll 4
    for (int k0 = 256; k0 < 512; k0 += 32) {
        bf16x8 a[2], b[4];
#pragma unroll
        for (int mi = 0; mi < 2; ++mi) {
            const float* s = h + (size_t)s_rows[mi * 16 + lrow] * HID + (k0 - 256) + kq;
            a[mi] = cvt8(((const float4*)s)[0], ((const float4*)s)[1]);
        }
#pragma unroll
        for (int ni = 0; ni < 4; ++ni)
            b[ni] = *(const bf16x8*)(Bg + (size_t)(n0 + ni * 16 + lrow) * KCAT + k0 + kq);
#pragma unroll
        for (int mi = 0; mi < 2; ++mi)
#pragma unroll
            for (int ni = 0; ni < 4; ++ni)
                acc[mi][ni] = __builtin_amdgcn_mfma_f32_16x16x32_bf16(
                    a[mi], b[ni], acc[mi][ni], 0, 0, 0);
    }

#pragma unroll
    for (int mi = 0; mi < 2; ++mi) {
#pragma unroll
        for (int r = 0; r < 4; ++r) {
            const int midx = mi * 16 + quad * 4 + r;
            if (mstart + midx >= cnt) continue;
            const int c = s_rows[midx];
#pragma unroll
            for (int ni = 0; ni < 4; ++ni) {
                const int k = n0 + ni * 16 + lrow;
                const float v = tanhf(acc[mi][ni][r]);
                ht_f32 [(size_t)c * HID + k] = v;
                ht_bf16[(size_t)c * HID + k] = f32_to_bf16_u16(v);
            }
        }
    }
}

// ---------------------------------------------------------------------------
// Stage 2: logits = ht . Vw^T + Vb   (M=2048, N=32000, K=256)
// R2 version verbatim (fastest measured): 128x128 tile, BK=32, double-
// buffered global_load_lds for BOTH operands (DMA -> no VGPR pressure,
// loads stay in flight across the barrier), source-side XOR swizzle,
// XCD n-major block swizzle, nontemporal C stores.
// ---------------------------------------------------------------------------
__global__ __launch_bounds__(256) void out_gemm_kernel(
    const unsigned short* __restrict__ A,   // ht bf16, 2048 x 256
    const unsigned short* __restrict__ B,   // Vw bf16, 32000 x 256
    const float* __restrict__ Vb,
    float* __restrict__ C)                  // 2048 x 32000
{
    __shared__ unsigned short sA[2][128 * 32];  // 8 KB per buffer
    __shared__ unsigned short sB[2][128 * 32];

    // bijective XCD swizzle (4000 = 8 * 500), n-major within an XCD chunk.
    const int id  = blockIdx.x;
    const int sid = (id & 7) * 500 + (id >> 3);
    const int n0  = (sid >> 4) * 128;       // 250 n-panels
    const int m0  = (sid & 15) * 128;       // 16 m-panels

    const int lane = threadIdx.x & 63;
    const int wave = threadIdx.x >> 6;
    const int wr = wave >> 1, wc = wave & 1;
    const int lrow = lane & 15;
    const int quad = lane >> 4;

    // staging: wave-load wl covers tile rows [wl*16, wl*16+16), 4 chunks/row.
    // HW writes lane l to slot (wl*16 + l>>2, l&3); source chunk pre-swizzled
    // so slot (r,s) holds global chunk s ^ ((r>>1)&3).
    const int srow   = lane >> 2;                       // row within wave-load
    const int schunk = (lane & 3) ^ ((lane >> 3) & 3);  // inverse-swizzled

    // read-side swizzled chunk slot: quad ^ ((row>>1)&3) == quad ^ ((lrow>>1)&3).
    const int rslot = quad ^ ((lrow >> 1) & 3);

    floatx4 acc[4][4] = {};

    // prologue: stage tile 0
#pragma unroll
    for (int it = 0; it < 2; ++it) {
        const int wl = wave * 2 + it;
        const int r  = wl * 16 + srow;
        lds_load16(&sA[0][wl * 512], A + (size_t)(m0 + r) * HID + schunk * 8);
        lds_load16(&sB[0][wl * 512], B + (size_t)(n0 + r) * HID + schunk * 8);
    }
    __syncthreads();

#pragma unroll
    for (int kt = 0; kt < 8; ++kt) {
        const int cur = kt & 1;
        if (kt < 7) {
            const int k0n = (kt + 1) * 32;
#pragma unroll
            for (int it = 0; it < 2; ++it) {
                const int wl = wave * 2 + it;
                const int r  = wl * 16 + srow;
                lds_load16(&sA[cur ^ 1][wl * 512],
                           A + (size_t)(m0 + r) * HID + k0n + schunk * 8);
                lds_load16(&sB[cur ^ 1][wl * 512],
                           B + (size_t)(n0 + r) * HID + k0n + schunk * 8);
            }
        }

        bf16x8 a[4], b[4];
#pragma unroll
        for (int mi = 0; mi < 4; ++mi) {
            const int ra = wr * 64 + mi * 16 + lrow;
            a[mi] = *(const bf16x8*)&sA[cur][ra * 32 + rslot * 8];
        }
#pragma unroll
        for (int ni = 0; ni < 4; ++ni) {
            const int rb = wc * 64 + ni * 16 + lrow;
            b[ni] = *(const bf16x8*)&sB[cur][rb * 32 + rslot * 8];
        }
#pragma unroll
        for (int mi = 0; mi < 4; ++mi)
#pragma unroll
            for (int ni = 0; ni < 4; ++ni)
                acc[mi][ni] = __builtin_amdgcn_mfma_f32_16x16x32_bf16(
                    a[mi], b[ni], acc[mi][ni], 0, 0, 0);

        __syncthreads();   // drains vmcnt (next tile staged) + lgkm (reads done)
    }

    const int m_wave = m0 + wr * 64;
    const int n_wave = n0 + wc * 64;
    const int row_q  = quad * 4;
#pragma unroll
    for (int ni = 0; ni < 4; ++ni) {
        const int col = n_wave + ni * 16 + lrow;
        const float vb = Vb[col];
#pragma unroll
        for (int mi = 0; mi < 4; ++mi) {
            float* cp = C + (size_t)(m_wave + mi * 16 + row_q) * VOCAB + col;
#pragma unroll
            for (int r = 0; r < 4; ++r)
                __builtin_nontemporal_store(acc[mi][ni][r] + vb, cp + (size_t)r * VOCAB);
        }
    }
}

extern "C" void kernel_launch(void* const* d_in, const int* in_sizes, int n_in,
                              void* d_out, int out_size, void* d_ws, size_t ws_size,
                              hipStream_t stream) {
    const int*   x  = (const int*)d_in[0];
    const int*   z  = (const int*)d_in[1];
    const float* h  = (const float*)d_in[2];
    const float* E  = (const float*)d_in[3];
    const float* Vw = (const float*)d_in[4];
    const float* Vb = (const float*)d_in[5];
    const float* W  = (const float*)d_in[6];
    const float* U  = (const float*)d_in[7];

    float* logits = (float*)d_out;
    float* ht_out = logits + (size_t)BATCH * VOCAB;

    // workspace layout
    char* p = (char*)d_ws;
    unsigned short* Vw_bf = (unsigned short*)p;  p += (size_t)VOCAB * HID * 2;
    unsigned short* ht_bf = (unsigned short*)p;  p += (size_t)BATCH * HID * 2;
    unsigned short* Bcat  = (unsigned short*)p;  p += (size_t)NUM_CLASS * HID * KCAT * 2;
    int* perm   = (int*)p;  p += BATCH * 4;
    int* counts = (int*)p;  p += NUM_CLASS * 4;
    int* bases  = (int*)p;  p += NUM_CLASS * 4;

    prep_bucket_kernel<<<PREP_BLOCKS + 1, 256, 0, stream>>>(
        W, U, Vw, z, Bcat, Vw_bf, perm, counts, bases);
    rnn_gemm_kernel<<<dim3(BATCH / 32, NUM_CLASS), 256, 0, stream>>>(
        x, E, h, Bcat, perm, counts, bases, ht_out, ht_bf);
    out_gemm_kernel<<<4000, 256, 0, stream>>>(ht_bf, Vw_bf, Vb, logits);
}

// Round 8
// 414.493 us; speedup vs baseline: 1.1838x; 1.0351x over previous
//
#include <hip/hip_runtime.h>
#include <hip/hip_bf16.h>

#define VOCAB 32000
#define NUM_CLASS 16
#define HID 256
#define KCAT 512          // concat(e, h) K dimension
#define BATCH 2048

typedef __attribute__((ext_vector_type(8))) __bf16 bf16x8;
typedef __attribute__((ext_vector_type(4))) float floatx4;

// RNE f32 -> bf16 (finite inputs)
__device__ __forceinline__ unsigned short f32_to_bf16_u16(float f) {
    union { float f; unsigned u; } a;
    a.f = f;
    unsigned r = a.u + 0x7fffu + ((a.u >> 16) & 1u);
    return (unsigned short)(r >> 16);
}

struct bf8v { unsigned short s[8]; };

// async global->LDS, 16B per lane. LDS dest is wave-uniform base + lane*16.
__device__ __forceinline__ void lds_load16(unsigned short* lds, const unsigned short* g) {
    __builtin_amdgcn_global_load_lds(
        (const __attribute__((address_space(1))) unsigned int*)g,
        (__attribute__((address_space(3))) unsigned int*)lds, 16, 0, 0);
}

// ---------------------------------------------------------------------------
// Fused prep + bucket (the 412.8 us configuration, verbatim).
// Blocks 0..5535: f32->bf16 staging (G, Bcat, Vw_bf).
//   G-staging is a COALESCING pass: E rows are read by 64 threads/row here,
//   vs scattered per-lane reads if folded into rnn_gemm (R7: +30 us, L3 cold).
// Block 5536: bucket batch elements by class into perm/counts/bases.
// ---------------------------------------------------------------------------
#define PREP_G   (BATCH * KCAT / 8)              // 131072
#define PREP_WU  (NUM_CLASS * HID * KCAT / 8)    // 262144
#define PREP_VW  (VOCAB * HID / 8)               // 1024000
#define PREP_TOT (PREP_G + PREP_WU + PREP_VW)    // 1417216 = 5536 * 256
#define PREP_BLOCKS (PREP_TOT / 256)             // 5536

__global__ __launch_bounds__(256) void prep_bucket_kernel(
    const int* __restrict__ x, const float* __restrict__ E,
    const float* __restrict__ h,
    const float* __restrict__ W, const float* __restrict__ U,
    const float* __restrict__ Vw, const int* __restrict__ z,
    unsigned short* __restrict__ G, unsigned short* __restrict__ Bcat,
    unsigned short* __restrict__ Vw_bf,
    int* __restrict__ perm, int* __restrict__ counts, int* __restrict__ bases)
{
    if (blockIdx.x == PREP_BLOCKS) {
        // ---- bucket ----
        __shared__ int s_cnt[NUM_CLASS];
        __shared__ int s_off[NUM_CLASS];
        const int t = threadIdx.x;
        if (t < NUM_CLASS) s_cnt[t] = 0;
        __syncthreads();
        for (int c = t; c < BATCH; c += 256) atomicAdd(&s_cnt[z[c]], 1);
        __syncthreads();
        if (t == 0) {
            int acc = 0;
            for (int i = 0; i < NUM_CLASS; ++i) { s_off[i] = acc; acc += s_cnt[i]; }
        }
        __syncthreads();
        if (t < NUM_CLASS) { counts[t] = s_cnt[t]; bases[t] = s_off[t]; }
        __syncthreads();
        for (int c = t; c < BATCH; c += 256) {
            int p = atomicAdd(&s_off[z[c]], 1);
            perm[p] = c;
        }
        return;
    }

    // ---- prep: load 2x float4, convert 8, store 16B ----
    const int tid = blockIdx.x * 256 + threadIdx.x;
    const float* src;
    unsigned short* dst;
    if (tid < PREP_G) {
        const int c  = tid >> 6;              // 64 chunks of 8 per row
        const int j0 = (tid & 63) * 8;
        src = (j0 < HID) ? (E + (size_t)x[c] * HID + j0)
                         : (h + (size_t)c * HID + (j0 - HID));
        dst = G + (size_t)c * KCAT + j0;
    } else if (tid < PREP_G + PREP_WU) {
        const int idx = tid - PREP_G;
        const int row = idx >> 6;             // g*HID + k
        const int j0  = (idx & 63) * 8;
        src = (j0 < HID) ? (W + (size_t)row * HID + j0)
                         : (U + (size_t)row * HID + (j0 - HID));
        dst = Bcat + (size_t)row * KCAT + j0;
    } else {
        const int idx = tid - (PREP_G + PREP_WU);
        src = Vw + (size_t)idx * 8;
        dst = Vw_bf + (size_t)idx * 8;
    }
    float4 v0 = ((const float4*)src)[0];
    float4 v1 = ((const float4*)src)[1];
    bf8v o;
    o.s[0] = f32_to_bf16_u16(v0.x); o.s[1] = f32_to_bf16_u16(v0.y);
    o.s[2] = f32_to_bf16_u16(v0.z); o.s[3] = f32_to_bf16_u16(v0.w);
    o.s[4] = f32_to_bf16_u16(v1.x); o.s[5] = f32_to_bf16_u16(v1.y);
    o.s[6] = f32_to_bf16_u16(v1.z); o.s[7] = f32_to_bf16_u16(v1.w);
    *(bf8v*)dst = o;
}

// ---------------------------------------------------------------------------
// Stage 1 as per-class GEMM: for class g, rows c in bucket:
//   ht[c][k] = tanh( G[c][:] . Bcat[g][k][:] )   (K = 512)
// Grid: (m_tile, class). Block 256 thr = 4 waves; tile M=32, N=256 (HID).
// ---------------------------------------------------------------------------
__global__ __launch_bounds__(256) void rnn_gemm_kernel(
    const unsigned short* __restrict__ G,     // BATCH x KCAT
    const unsigned short* __restrict__ Bcat,  // NUM_CLASS x HID x KCAT
    const int* __restrict__ perm, const int* __restrict__ counts,
    const int* __restrict__ bases,
    float* __restrict__ ht_f32, unsigned short* __restrict__ ht_bf16)
{
    const int g = blockIdx.y;
    const int cnt = counts[g];
    const int mstart = blockIdx.x * 32;
    if (mstart >= cnt) return;
    const int base = bases[g];

    __shared__ int s_rows[32];
    if (threadIdx.x < 32) {
        int mi = mstart + threadIdx.x;
        s_rows[threadIdx.x] = perm[base + (mi < cnt ? mi : cnt - 1)];
    }
    __syncthreads();

    const int lane = threadIdx.x & 63;
    const int wave = threadIdx.x >> 6;
    const int n0   = wave * 64;
    const int lrow = lane & 15;
    const int quad = lane >> 4;
    const int kq   = quad * 8;

    const unsigned short* Bg = Bcat + (size_t)g * HID * KCAT;

    floatx4 acc[2][4] = {};
#pragma unroll 4
    for (int k0 = 0; k0 < KCAT; k0 += 32) {
        bf16x8 a[2], b[4];
#pragma unroll
        for (int mi = 0; mi < 2; ++mi) {
            const int row = s_rows[mi * 16 + lrow];
            a[mi] = *(const bf16x8*)(G + (size_t)row * KCAT + k0 + kq);
        }
#pragma unroll
        for (int ni = 0; ni < 4; ++ni)
            b[ni] = *(const bf16x8*)(Bg + (size_t)(n0 + ni * 16 + lrow) * KCAT + k0 + kq);
#pragma unroll
        for (int mi = 0; mi < 2; ++mi)
#pragma unroll
            for (int ni = 0; ni < 4; ++ni)
                acc[mi][ni] = __builtin_amdgcn_mfma_f32_16x16x32_bf16(
                    a[mi], b[ni], acc[mi][ni], 0, 0, 0);
    }

#pragma unroll
    for (int mi = 0; mi < 2; ++mi) {
#pragma unroll
        for (int r = 0; r < 4; ++r) {
            const int midx = mi * 16 + quad * 4 + r;
            if (mstart + midx >= cnt) continue;
            const int c = s_rows[midx];
#pragma unroll
            for (int ni = 0; ni < 4; ++ni) {
                const int k = n0 + ni * 16 + lrow;
                const float v = tanhf(acc[mi][ni][r]);
                ht_f32 [(size_t)c * HID + k] = v;
                ht_bf16[(size_t)c * HID + k] = f32_to_bf16_u16(v);
            }
        }
    }
}

// ---------------------------------------------------------------------------
// Stage 2: logits = ht . Vw^T + Vb   (M=2048, N=32000, K=256)
// 128x128 tile, BK=32, double-buffered global_load_lds staging: stage(t+1)
// issued before compute(t), one barrier per tile. Source-side XOR swizzle
// (slot (r,s) holds chunk s ^ ((r>>1)&3)); reads are 2-way bank (free).
// XCD n-major block swizzle; nontemporal C stores.
// ---------------------------------------------------------------------------
__global__ __launch_bounds__(256) void out_gemm_kernel(
    const unsigned short* __restrict__ A,   // ht bf16, 2048 x 256
    const unsigned short* __restrict__ B,   // Vw bf16, 32000 x 256
    const float* __restrict__ Vb,
    float* __restrict__ C)                  // 2048 x 32000
{
    __shared__ unsigned short sA[2][128 * 32];  // 8 KB per buffer
    __shared__ unsigned short sB[2][128 * 32];

    // bijective XCD swizzle (4000 = 8 * 500), n-major within an XCD chunk.
    const int id  = blockIdx.x;
    const int sid = (id & 7) * 500 + (id >> 3);
    const int n0  = (sid >> 4) * 128;       // 250 n-panels
    const int m0  = (sid & 15) * 128;       // 16 m-panels

    const int lane = threadIdx.x & 63;
    const int wave = threadIdx.x >> 6;
    const int wr = wave >> 1, wc = wave & 1;
    const int lrow = lane & 15;
    const int quad = lane >> 4;

    // staging: wave-load wl covers tile rows [wl*16, wl*16+16), 4 chunks/row.
    const int srow   = lane >> 2;                       // row within wave-load
    const int schunk = (lane & 3) ^ ((lane >> 3) & 3);  // inverse-swizzled

    // read-side swizzled chunk slot.
    const int rslot = quad ^ ((lrow >> 1) & 3);

    floatx4 acc[4][4] = {};

    // prologue: stage tile 0
#pragma unroll
    for (int it = 0; it < 2; ++it) {
        const int wl = wave * 2 + it;
        const int r  = wl * 16 + srow;
        lds_load16(&sA[0][wl * 512], A + (size_t)(m0 + r) * HID + schunk * 8);
        lds_load16(&sB[0][wl * 512], B + (size_t)(n0 + r) * HID + schunk * 8);
    }
    __syncthreads();

#pragma unroll
    for (int kt = 0; kt < 8; ++kt) {
        const int cur = kt & 1;
        if (kt < 7) {
            const int k0n = (kt + 1) * 32;
#pragma unroll
            for (int it = 0; it < 2; ++it) {
                const int wl = wave * 2 + it;
                const int r  = wl * 16 + srow;
                lds_load16(&sA[cur ^ 1][wl * 512],
                           A + (size_t)(m0 + r) * HID + k0n + schunk * 8);
                lds_load16(&sB[cur ^ 1][wl * 512],
                           B + (size_t)(n0 + r) * HID + k0n + schunk * 8);
            }
        }

        bf16x8 a[4], b[4];
#pragma unroll
        for (int mi = 0; mi < 4; ++mi) {
            const int ra = wr * 64 + mi * 16 + lrow;
            a[mi] = *(const bf16x8*)&sA[cur][ra * 32 + rslot * 8];
        }
#pragma unroll
        for (int ni = 0; ni < 4; ++ni) {
            const int rb = wc * 64 + ni * 16 + lrow;
            b[ni] = *(const bf16x8*)&sB[cur][rb * 32 + rslot * 8];
        }
#pragma unroll
        for (int mi = 0; mi < 4; ++mi)
#pragma unroll
            for (int ni = 0; ni < 4; ++ni)
                acc[mi][ni] = __builtin_amdgcn_mfma_f32_16x16x32_bf16(
                    a[mi], b[ni], acc[mi][ni], 0, 0, 0);

        __syncthreads();   // drains vmcnt (next tile staged) + lgkm (reads done)
    }

    const int m_wave = m0 + wr * 64;
    const int n_wave = n0 + wc * 64;
    const int row_q  = quad * 4;
#pragma unroll
    for (int ni = 0; ni < 4; ++ni) {
        const int col = n_wave + ni * 16 + lrow;
        const float vb = Vb[col];
#pragma unroll
        for (int mi = 0; mi < 4; ++mi) {
            float* cp = C + (size_t)(m_wave + mi * 16 + row_q) * VOCAB + col;
#pragma unroll
            for (int r = 0; r < 4; ++r)
                __builtin_nontemporal_store(acc[mi][ni][r] + vb, cp + (size_t)r * VOCAB);
        }
    }
}

extern "C" void kernel_launch(void* const* d_in, const int* in_sizes, int n_in,
                              void* d_out, int out_size, void* d_ws, size_t ws_size,
                              hipStream_t stream) {
    const int*   x  = (const int*)d_in[0];
    const int*   z  = (const int*)d_in[1];
    const float* h  = (const float*)d_in[2];
    const float* E  = (const float*)d_in[3];
    const float* Vw = (const float*)d_in[4];
    const float* Vb = (const float*)d_in[5];
    const float* W  = (const float*)d_in[6];
    const float* U  = (const float*)d_in[7];

    float* logits = (float*)d_out;
    float* ht_out = logits + (size_t)BATCH * VOCAB;

    // workspace layout
    char* p = (char*)d_ws;
    unsigned short* Vw_bf = (unsigned short*)p;  p += (size_t)VOCAB * HID * 2;
    unsigned short* ht_bf = (unsigned short*)p;  p += (size_t)BATCH * HID * 2;
    unsigned short* G     = (unsigned short*)p;  p += (size_t)BATCH * KCAT * 2;
    unsigned short* Bcat  = (unsigned short*)p;  p += (size_t)NUM_CLASS * HID * KCAT * 2;
    int* perm   = (int*)p;  p += BATCH * 4;
    int* counts = (int*)p;  p += NUM_CLASS * 4;
    int* bases  = (int*)p;  p += NUM_CLASS * 4;

    prep_bucket_kernel<<<PREP_BLOCKS + 1, 256, 0, stream>>>(
        x, E, h, W, U, Vw, z, G, Bcat, Vw_bf, perm, counts, bases);
    rnn_gemm_kernel<<<dim3(BATCH / 32, NUM_CLASS), 256, 0, stream>>>(
        G, Bcat, perm, counts, bases, ht_out, ht_bf);
    out_gemm_kernel<<<4000, 256, 0, stream>>>(ht_bf, Vw_bf, Vb, logits);
}